// Round 2
// baseline (9513.658 us; speedup 1.0000x reference)
//
#include <hip/hip_runtime.h>

// Problem constants
#define BB   512            // batch
#define TT   128            // time steps
#define DD   512            // d_dyn
#define DS   256            // d_static
#define UD   128            // u_dim
#define NO   40             // n_obs
#define G4   2048           // 4*DD
#define KY   640            // DD + UD (output head K)
#define NY   48             // padded n_obs

#define NRG  8              // row groups (64 rows each) -> one per XCD
#define NCS  32             // col slices (16 d-cols each)
#define KP0  648            // 640 + 8 pad (bank stride 4 mod 32, 16B aligned)
#define KP1  520            // 512 + 8 pad
#define LDSB (64*KP0*2 + 64*KP1*2)   // 82944 + 66560 = 149504 bytes

typedef __bf16 bf16x8 __attribute__((ext_vector_type(8)));
typedef float  f32x4  __attribute__((ext_vector_type(4)));

__device__ __forceinline__ f32x4 mfma16(bf16x8 a, bf16x8 b, f32x4 c) {
  return __builtin_amdgcn_mfma_f32_16x16x32_bf16(a, b, c, 0, 0, 0);
}

__device__ __forceinline__ float sigm(float x)     { return 1.0f / (1.0f + __expf(-x)); }
__device__ __forceinline__ float tanhfast(float x) { return 2.0f / (1.0f + __expf(-2.0f * x)) - 1.0f; }

__device__ __forceinline__ bf16x8 cvt8(const float* __restrict__ p) {
  const float4 u0 = *reinterpret_cast<const float4*>(p);
  const float4 u1 = *reinterpret_cast<const float4*>(p + 4);
  bf16x8 r;
  r[0] = (__bf16)u0.x; r[1] = (__bf16)u0.y; r[2] = (__bf16)u0.z; r[3] = (__bf16)u0.w;
  r[4] = (__bf16)u1.x; r[5] = (__bf16)u1.y; r[6] = (__bf16)u1.z; r[7] = (__bf16)u1.w;
  return r;
}
__device__ __forceinline__ bf16x8 cvt8s(const float* __restrict__ p, float s) {
  const float4 u0 = *reinterpret_cast<const float4*>(p);
  const float4 u1 = *reinterpret_cast<const float4*>(p + 4);
  bf16x8 r;
  r[0] = (__bf16)(u0.x*s); r[1] = (__bf16)(u0.y*s); r[2] = (__bf16)(u0.z*s); r[3] = (__bf16)(u0.w*s);
  r[4] = (__bf16)(u1.x*s); r[5] = (__bf16)(u1.y*s); r[6] = (__bf16)(u1.z*s); r[7] = (__bf16)(u1.w*s);
  return r;
}

// ---------------- one-time prep: biases, head weights, state init, flags ----------------
__global__ __launch_bounds__(256) void prep_kernel(
    const float* __restrict__ z_dyn,
    const float* __restrict__ bih1, const float* __restrict__ bhh1,
    const float* __restrict__ Cw,   const float* __restrict__ Dw,
    float* __restrict__ b1sum, __bf16* __restrict__ CD,
    __bf16* __restrict__ hbuf, int* __restrict__ flags)
{
  int idx = blockIdx.x * 256 + threadIdx.x;
  if (idx < NRG * NCS * 16) flags[idx] = 0;
  if (idx < G4) b1sum[idx] = bih1[idx] + bhh1[idx];
  if (idx < NY * KY) {
    int o = idx / KY, k = idx - o * KY;
    float v = 0.f;
    if (o < NO) v = (k < DD) ? Cw[o * DD + k] : Dw[o * UD + (k - DD)];
    CD[idx] = (__bf16)v;
  }
  if (idx < BB * DD) hbuf[idx] = (__bf16)z_dyn[idx];
}

// ---------------- one-time: pre0[b,j] = z_static @ Wih0[:,128:384]^T + bih0 + bhh0 ----
__global__ __launch_bounds__(256) void pre0_kernel(
    const float* __restrict__ z_static, const float* __restrict__ Wih0,
    const float* __restrict__ bih0, const float* __restrict__ bhh0,
    float* __restrict__ pre0)
{
  int lane = threadIdx.x & 63, w = threadIdx.x >> 6;
  int rm = lane & 15;
  int row = blockIdx.x * 64 + w * 16 + rm;
  int j0 = blockIdx.y * 64;
  int klane = (lane >> 4) * 8;
  f32x4 acc[4] = {};
  for (int k0 = 0; k0 < DS; k0 += 32) {
    int k = k0 + klane;
    bf16x8 a = cvt8(&z_static[row * DS + k]);
#pragma unroll
    for (int cf = 0; cf < 4; ++cf) {
      int j = j0 + cf * 16 + rm;
      bf16x8 b = cvt8(&Wih0[j * (UD + DS) + UD + k]);
      acc[cf] = mfma16(a, b, acc[cf]);
    }
  }
  int rbase = blockIdx.x * 64 + w * 16 + (lane >> 4) * 4;
#pragma unroll
  for (int cf = 0; cf < 4; ++cf) {
    int j = j0 + cf * 16 + rm;
    float bj = bih0[j] + bhh0[j];
#pragma unroll
    for (int q = 0; q < 4; ++q)
      pre0[(size_t)(rbase + q) * G4 + j] = acc[cf][q] + bj;
  }
}

// ---------------- row-group flag barrier ----------------
__device__ __forceinline__ void rg_barrier(int* __restrict__ myflag,
                                           int* __restrict__ flags,
                                           int r, int epoch, int& budget)
{
  __threadfence();
  __syncthreads();
  if (threadIdx.x == 0)
    __hip_atomic_store(myflag, epoch, __ATOMIC_RELEASE, __HIP_MEMORY_SCOPE_AGENT);
  if (threadIdx.x < 64) {
    const int idx = threadIdx.x & 31;
    const int* f = &flags[(r * NCS + idx) * 16];
    while (__hip_atomic_load(f, __ATOMIC_RELAXED, __HIP_MEMORY_SCOPE_AGENT) < epoch) {
      if (--budget < 0) break;   // emergency bail: wrong results, no hang
      __builtin_amdgcn_s_sleep(2);
    }
  }
  __syncthreads();
  __builtin_amdgcn_fence(__ATOMIC_ACQUIRE, "agent");
}

// ---------------- persistent scan kernel ----------------
// 256 blocks x 256 threads. block (r = bid&7, c = bid>>3):
//   owns rows [r*64, r*64+64), d-cols [c*16, c*16+16) (x4 gates = 64 gate-cols).
// Weights for its 64 gate-cols live in LDS ([col][k], padded stride).
// Wave w: rows r*64+w*16..+16, all 64 gate-cols (gate-complete -> lane-local LSTM cell).
__global__ __launch_bounds__(256, 1) void persist_kernel(
    const float* __restrict__ U, const float* __restrict__ dtp,
    const float* __restrict__ Wih0, const float* __restrict__ Whh0,
    const float* __restrict__ Wih1, const float* __restrict__ Whh1,
    const float* __restrict__ pre0, const float* __restrict__ b1sum,
    __bf16* __restrict__ hbuf, __bf16* __restrict__ h1buf,
    int* __restrict__ flags, float* __restrict__ Z)
{
  extern __shared__ __align__(16) char smem[];
  __bf16* W0L = (__bf16*)smem;                     // [64][KP0]
  __bf16* W1L = (__bf16*)(smem + 64 * KP0 * 2);    // [64][KP1]

  const int tid = threadIdx.x;
  const int r = blockIdx.x & 7, c = blockIdx.x >> 3;

  // stage weights into LDS (one-time)
  for (int idx = tid; idx < 64 * 640; idx += 256) {
    int col = idx / 640, k = idx - col * 640;      // col = g*16 + i
    int g = col >> 4, i = col & 15;
    int j = g * DD + c * 16 + i;
    float v = (k < UD) ? Wih0[(size_t)j * (UD + DS) + k]
                       : Whh0[(size_t)j * DD + (k - UD)];
    W0L[col * KP0 + k] = (__bf16)v;
  }
  for (int idx = tid; idx < 64 * 512; idx += 256) {
    int col = idx >> 9, k = idx & 511;
    int g = col >> 4, i = col & 15;
    int j = g * DD + c * 16 + i;
    W1L[col * KP1 + k] = (__bf16)(Wih1[(size_t)j * DD + k] + Whh1[(size_t)j * DD + k]);
  }

  const int lane = tid & 63, w = tid >> 6;
  const int rm = lane & 15, lh = lane >> 4;
  const int klane = lh * 8;
  const int arow  = r * 64 + w * 16 + rm;          // MFMA A-frag row
  const int dcol  = c * 16 + rm;                   // output d col (C-layout col)
  const int rbase = r * 64 + w * 16 + lh * 4;      // C-layout rows rbase+q
  const float dtv = dtp[0];

  // per-thread resident biases (match acc fragment layout)
  float preR[4][4], b1R[4];
#pragma unroll
  for (int g = 0; g < 4; ++g) {
    b1R[g] = b1sum[g * DD + dcol];
#pragma unroll
    for (int q = 0; q < 4; ++q)
      preR[g][q] = pre0[(size_t)(rbase + q) * G4 + g * DD + dcol];
  }

  float c1v[4] = {0.f, 0.f, 0.f, 0.f};
  float c2v[4] = {0.f, 0.f, 0.f, 0.f};
  int* myflag = &flags[(r * NCS + c) * 16];
  int budget = 1 << 21;

  __syncthreads();

  for (int t = 0; t < TT; ++t) {
    const float* Ut = U + (size_t)t * BB * UD;

    // ---- layer 0: gates = [u*dt | h_prev] @ W0^T + pre0 ----
    f32x4 acc[4] = {};
#pragma unroll
    for (int k0 = 0; k0 < 640; k0 += 32) {
      bf16x8 a;
      if (k0 < UD) a = cvt8s(&Ut[(size_t)arow * UD + k0 + klane], dtv);
      else a = *reinterpret_cast<const bf16x8*>(&hbuf[(size_t)arow * DD + (k0 - UD) + klane]);
#pragma unroll
      for (int g = 0; g < 4; ++g) {
        bf16x8 b = *reinterpret_cast<const bf16x8*>(&W0L[(g * 16 + rm) * KP0 + k0 + klane]);
        acc[g] = mfma16(a, b, acc[g]);
      }
    }
#pragma unroll
    for (int q = 0; q < 4; ++q) {
      float gi = acc[0][q] + preR[0][q];
      float gf = acc[1][q] + preR[1][q];
      float gg = acc[2][q] + preR[2][q];
      float go = acc[3][q] + preR[3][q];
      float cn = sigm(gf) * c1v[q] + sigm(gi) * tanhfast(gg);
      c1v[q] = cn;
      float hn = sigm(go) * tanhfast(cn);
      h1buf[(size_t)(rbase + q) * DD + dcol] = (__bf16)hn;
    }
    rg_barrier(myflag, flags, r, 2 * t + 1, budget);

    // ---- layer 1: gates = h1 @ (Wih1+Whh1)^T + b1sum ----
    f32x4 acc2[4] = {};
#pragma unroll
    for (int k0 = 0; k0 < 512; k0 += 32) {
      bf16x8 a = *reinterpret_cast<const bf16x8*>(&h1buf[(size_t)arow * DD + k0 + klane]);
#pragma unroll
      for (int g = 0; g < 4; ++g) {
        bf16x8 b = *reinterpret_cast<const bf16x8*>(&W1L[(g * 16 + rm) * KP1 + k0 + klane]);
        acc2[g] = mfma16(a, b, acc2[g]);
      }
    }
    float* Zt = Z + (size_t)t * BB * DD;
#pragma unroll
    for (int q = 0; q < 4; ++q) {
      float gi = acc2[0][q] + b1R[0];
      float gf = acc2[1][q] + b1R[1];
      float gg = acc2[2][q] + b1R[2];
      float go = acc2[3][q] + b1R[3];
      float cn = sigm(gf) * c2v[q] + sigm(gi) * tanhfast(gg);
      c2v[q] = cn;
      float hn = sigm(go) * tanhfast(cn);
      hbuf[(size_t)(rbase + q) * DD + dcol] = (__bf16)hn;
      Zt[(size_t)(rbase + q) * DD + dcol] = hn;
    }
    rg_barrier(myflag, flags, r, 2 * t + 2, budget);
  }
}

// ---------------- batched output head: Y = [Z | dt*U] @ CD^T ----------------
__global__ __launch_bounds__(256) void y_kernel(
    const float* __restrict__ Z, const float* __restrict__ U,
    const float* __restrict__ dtp, const __bf16* __restrict__ CD,
    float* __restrict__ Y)
{
  int lane = threadIdx.x & 63, w = threadIdx.x >> 6;
  int rm = lane & 15;
  int rowbase = blockIdx.x * 128 + w * 32;
  int klane = (lane >> 4) * 8;
  float dtv = dtp[0];
  f32x4 acc[2][3] = {};
#pragma unroll
  for (int k0 = 0; k0 < KY; k0 += 32) {
    int k = k0 + klane;
    bf16x8 a[2];
#pragma unroll
    for (int rb = 0; rb < 2; ++rb) {
      int rr = rowbase + rb * 16 + rm;
      if (k0 < DD) a[rb] = cvt8(&Z[(size_t)rr * DD + k]);
      else         a[rb] = cvt8s(&U[(size_t)rr * UD + (k - DD)], dtv);
    }
#pragma unroll
    for (int cf = 0; cf < 3; ++cf) {
      bf16x8 b = *reinterpret_cast<const bf16x8*>(&CD[(size_t)(cf * 16 + rm) * KY + k]);
#pragma unroll
      for (int rb = 0; rb < 2; ++rb) acc[rb][cf] = mfma16(a[rb], b, acc[rb][cf]);
    }
  }
#pragma unroll
  for (int rb = 0; rb < 2; ++rb)
#pragma unroll
    for (int cf = 0; cf < 3; ++cf) {
      int n = cf * 16 + rm;
      if (n < NO)
#pragma unroll
        for (int q = 0; q < 4; ++q) {
          int rr = rowbase + rb * 16 + (lane >> 4) * 4 + q;
          Y[(size_t)rr * NO + n] = acc[rb][cf][q];
        }
    }
}

extern "C" void kernel_launch(void* const* d_in, const int* in_sizes, int n_in,
                              void* d_out, int out_size, void* d_ws, size_t ws_size,
                              hipStream_t stream) {
  const float* z_dyn    = (const float*)d_in[0];
  const float* z_static = (const float*)d_in[1];
  const float* dt       = (const float*)d_in[2];
  const float* U        = (const float*)d_in[3];
  const float* Wih0     = (const float*)d_in[4];
  const float* Whh0     = (const float*)d_in[5];
  const float* bih0     = (const float*)d_in[6];
  const float* bhh0     = (const float*)d_in[7];
  const float* Wih1     = (const float*)d_in[8];
  const float* Whh1     = (const float*)d_in[9];
  const float* bih1     = (const float*)d_in[10];
  const float* bhh1     = (const float*)d_in[11];
  const float* Cw       = (const float*)d_in[12];
  const float* Dw       = (const float*)d_in[13];

  float* out = (float*)d_out;
  float* Z = out;                                       // [TT, BB, DD]
  float* Y = out + (size_t)TT * BB * DD;                // [TT, BB, NO]

  char* p = (char*)d_ws;
  auto carve = [&](size_t bytes) {
    void* r = (void*)p;
    p += (bytes + 255) & ~(size_t)255;
    return r;
  };
  float*  b1sum  = (float*)carve((size_t)G4 * 4);
  __bf16* CD     = (__bf16*)carve((size_t)NY * KY * 2);
  float*  pre0   = (float*)carve((size_t)BB * G4 * 4);
  __bf16* hbuf   = (__bf16*)carve((size_t)BB * DD * 2);
  __bf16* h1buf  = (__bf16*)carve((size_t)BB * DD * 2);
  int*    flags  = (int*)carve((size_t)NRG * NCS * 16 * 4);

  prep_kernel<<<1024, 256, 0, stream>>>(z_dyn, bih1, bhh1, Cw, Dw,
                                        b1sum, CD, hbuf, flags);
  pre0_kernel<<<dim3(8, 32), 256, 0, stream>>>(z_static, Wih0, bih0, bhh0, pre0);

  persist_kernel<<<256, 256, LDSB, stream>>>(
      U, dt, Wih0, Whh0, Wih1, Whh1, pre0, b1sum, hbuf, h1buf, flags, Z);

  y_kernel<<<512, 256, 0, stream>>>(Z, U, dt, CD, Y);
}

// Round 3
// 1587.094 us; speedup vs baseline: 5.9944x; 5.9944x over previous
//
#include <hip/hip_runtime.h>

// Problem constants
#define BB   512            // batch
#define TT   128            // time steps
#define DD   512            // d_dyn
#define DS   256            // d_static
#define UD   128            // u_dim
#define NO   40             // n_obs
#define G4   2048           // 4*DD
#define KY   640            // DD + UD (output head K)
#define NY   48             // padded n_obs

#define NRG  8              // row groups (64 rows each)
#define NCS  32             // col slices (16 d-cols each)
#define KP0  648            // 640 + 8 pad
#define KP1  520            // 512 + 8 pad
#define LDSB (64*KP0*2 + 64*KP1*2)   // 149504 bytes

typedef __bf16 bf16x8 __attribute__((ext_vector_type(8)));
typedef float  f32x4  __attribute__((ext_vector_type(4)));

__device__ __forceinline__ f32x4 mfma16(bf16x8 a, bf16x8 b, f32x4 c) {
  return __builtin_amdgcn_mfma_f32_16x16x32_bf16(a, b, c, 0, 0, 0);
}

__device__ __forceinline__ float sigm(float x)     { return 1.0f / (1.0f + __expf(-x)); }
__device__ __forceinline__ float tanhfast(float x) { return 2.0f / (1.0f + __expf(-2.0f * x)) - 1.0f; }

__device__ __forceinline__ bf16x8 cvt8(const float* __restrict__ p) {
  const float4 u0 = *reinterpret_cast<const float4*>(p);
  const float4 u1 = *reinterpret_cast<const float4*>(p + 4);
  bf16x8 r;
  r[0] = (__bf16)u0.x; r[1] = (__bf16)u0.y; r[2] = (__bf16)u0.z; r[3] = (__bf16)u0.w;
  r[4] = (__bf16)u1.x; r[5] = (__bf16)u1.y; r[6] = (__bf16)u1.z; r[7] = (__bf16)u1.w;
  return r;
}
__device__ __forceinline__ bf16x8 cvt8s(const float* __restrict__ p, float s) {
  const float4 u0 = *reinterpret_cast<const float4*>(p);
  const float4 u1 = *reinterpret_cast<const float4*>(p + 4);
  bf16x8 r;
  r[0] = (__bf16)(u0.x*s); r[1] = (__bf16)(u0.y*s); r[2] = (__bf16)(u0.z*s); r[3] = (__bf16)(u0.w*s);
  r[4] = (__bf16)(u1.x*s); r[5] = (__bf16)(u1.y*s); r[6] = (__bf16)(u1.z*s); r[7] = (__bf16)(u1.w*s);
  return r;
}

// L1/L2-bypass 16B load (coherence-point read). IMM = byte offset literal.
#define LD_IC(dst, base, IMM)                                              \
  asm volatile("global_load_dwordx4 %0, %1, off offset:" #IMM " sc0 sc1"   \
               : "=v"(dst) : "v"(base));

// store one bf16 value at the coherence point (bypasses L1/L2, no fence)
__device__ __forceinline__ void st_ic(__bf16* p, float v) {
  __bf16 h = (__bf16)v;
  unsigned short us = __builtin_bit_cast(unsigned short, h);
  __hip_atomic_store((unsigned short*)p, us, __ATOMIC_RELAXED, __HIP_MEMORY_SCOPE_AGENT);
}

// ---------------- one-time prep ----------------
__global__ __launch_bounds__(256) void prep_kernel(
    const float* __restrict__ z_dyn,
    const float* __restrict__ bih1, const float* __restrict__ bhh1,
    const float* __restrict__ Cw,   const float* __restrict__ Dw,
    float* __restrict__ b1sum, __bf16* __restrict__ CD,
    __bf16* __restrict__ hbuf, int* __restrict__ flags)
{
  int idx = blockIdx.x * 256 + threadIdx.x;
  if (idx < NRG * NCS * 16) flags[idx] = 0;
  if (idx < G4) b1sum[idx] = bih1[idx] + bhh1[idx];
  if (idx < NY * KY) {
    int o = idx / KY, k = idx - o * KY;
    float v = 0.f;
    if (o < NO) v = (k < DD) ? Cw[o * DD + k] : Dw[o * UD + (k - DD)];
    CD[idx] = (__bf16)v;
  }
  if (idx < BB * DD) hbuf[idx] = (__bf16)z_dyn[idx];
}

// ---------------- pre0[b,j] = z_static @ Wih0[:,128:384]^T + bih0 + bhh0 ----
__global__ __launch_bounds__(256) void pre0_kernel(
    const float* __restrict__ z_static, const float* __restrict__ Wih0,
    const float* __restrict__ bih0, const float* __restrict__ bhh0,
    float* __restrict__ pre0)
{
  int lane = threadIdx.x & 63, w = threadIdx.x >> 6;
  int rm = lane & 15;
  int row = blockIdx.x * 64 + w * 16 + rm;
  int j0 = blockIdx.y * 64;
  int klane = (lane >> 4) * 8;
  f32x4 acc[4] = {};
  for (int k0 = 0; k0 < DS; k0 += 32) {
    int k = k0 + klane;
    bf16x8 a = cvt8(&z_static[row * DS + k]);
#pragma unroll
    for (int cf = 0; cf < 4; ++cf) {
      int j = j0 + cf * 16 + rm;
      bf16x8 b = cvt8(&Wih0[j * (UD + DS) + UD + k]);
      acc[cf] = mfma16(a, b, acc[cf]);
    }
  }
  int rbase = blockIdx.x * 64 + w * 16 + (lane >> 4) * 4;
#pragma unroll
  for (int cf = 0; cf < 4; ++cf) {
    int j = j0 + cf * 16 + rm;
    float bj = bih0[j] + bhh0[j];
#pragma unroll
    for (int q = 0; q < 4; ++q)
      pre0[(size_t)(rbase + q) * G4 + j] = acc[cf][q] + bj;
  }
}

// ---------------- fence-free row-group flag barrier ----------------
// Communicated data travels via IC (atomic stores / sc0sc1 loads), so no
// L2 writeback/invalidate is needed — only store-completion + flag exchange.
__device__ __forceinline__ void rg_barrier(int* myflag, int* flags,
                                           int r, int epoch, int& budget)
{
  asm volatile("s_waitcnt vmcnt(0)" ::: "memory");   // my stores are at IC
  __syncthreads();                                   // whole block done
  if (threadIdx.x == 0)
    __hip_atomic_store(myflag, epoch, __ATOMIC_RELAXED, __HIP_MEMORY_SCOPE_AGENT);
  if (threadIdx.x < 32) {
    int* f = &flags[(r * NCS + threadIdx.x) * 16];
    while (__hip_atomic_load(f, __ATOMIC_RELAXED, __HIP_MEMORY_SCOPE_AGENT) < epoch) {
      if (--budget < 0) break;                       // hang guard
      __builtin_amdgcn_s_sleep(2);
    }
  }
  __syncthreads();
}

// ---------------- persistent scan kernel ----------------
// 256 blocks x 256 threads. block (r = bid&7, c = bid>>3):
//   rows [r*64, +64), d-cols [c*16, +16) x 4 gates. Weights in LDS.
__global__ __launch_bounds__(256, 1) void persist_kernel(
    const float* __restrict__ U, const float* __restrict__ dtp,
    const float* __restrict__ Wih0, const float* __restrict__ Whh0,
    const float* __restrict__ Wih1, const float* __restrict__ Whh1,
    const float* __restrict__ pre0, const float* __restrict__ b1sum,
    __bf16* __restrict__ hbuf, __bf16* __restrict__ h1buf,
    int* __restrict__ flags, float* __restrict__ Z)
{
  extern __shared__ __align__(16) char smem[];
  __bf16* W0L = (__bf16*)smem;                     // [64][KP0]
  __bf16* W1L = (__bf16*)(smem + 64 * KP0 * 2);    // [64][KP1]

  const int tid = threadIdx.x;
  const int r = blockIdx.x & 7, c = blockIdx.x >> 3;

  // stage weights into LDS (one-time)
  for (int idx = tid; idx < 64 * 640; idx += 256) {
    int col = idx / 640, k = idx - col * 640;      // col = g*16 + i
    int g = col >> 4, i = col & 15;
    int j = g * DD + c * 16 + i;
    float v = (k < UD) ? Wih0[(size_t)j * (UD + DS) + k]
                       : Whh0[(size_t)j * DD + (k - UD)];
    W0L[col * KP0 + k] = (__bf16)v;
  }
  for (int idx = tid; idx < 64 * 512; idx += 256) {
    int col = idx >> 9, k = idx & 511;
    int g = col >> 4, i = col & 15;
    int j = g * DD + c * 16 + i;
    W1L[col * KP1 + k] = (__bf16)(Wih1[(size_t)j * DD + k] + Whh1[(size_t)j * DD + k]);
  }

  const int lane = tid & 63, w = tid >> 6;
  const int rm = lane & 15, lh = lane >> 4;
  const int klane = lh * 8;
  const int arow  = r * 64 + w * 16 + rm;          // MFMA A-frag row
  const int dcol  = c * 16 + rm;                   // output d col
  const int rbase = r * 64 + w * 16 + lh * 4;      // C rows rbase+q
  const float dtv = dtp[0];

  // resident biases (match acc fragment layout)
  float preR[4][4], b1R[4];
#pragma unroll
  for (int g = 0; g < 4; ++g) {
    b1R[g] = b1sum[g * DD + dcol];
#pragma unroll
    for (int q = 0; q < 4; ++q)
      preR[g][q] = pre0[(size_t)(rbase + q) * G4 + g * DD + dcol];
  }

  float c1v[4] = {0.f, 0.f, 0.f, 0.f};
  float c2v[4] = {0.f, 0.f, 0.f, 0.f};
  int* myflag = &flags[(r * NCS + c) * 16];
  int budget = 1 << 19;

  const __bf16* hb_base  = hbuf  + (size_t)arow * DD + klane;
  const __bf16* h1_base  = h1buf + (size_t)arow * DD + klane;

  __syncthreads();

  for (int t = 0; t < TT; ++t) {
    const float* Ut = U + (size_t)t * BB * UD;

    // ---- layer 0: gates = [u*dt | h_prev] @ W0^T + pre0 ----
    bf16x8 ah0, ah1, ah2, ah3, ah4, ah5, ah6, ah7;
    bf16x8 ah8, ah9, ahA, ahB, ahC, ahD, ahE, ahF;
    LD_IC(ah0, hb_base, 0)    LD_IC(ah1, hb_base, 64)
    LD_IC(ah2, hb_base, 128)  LD_IC(ah3, hb_base, 192)
    LD_IC(ah4, hb_base, 256)  LD_IC(ah5, hb_base, 320)
    LD_IC(ah6, hb_base, 384)  LD_IC(ah7, hb_base, 448)
    LD_IC(ah8, hb_base, 512)  LD_IC(ah9, hb_base, 576)
    LD_IC(ahA, hb_base, 640)  LD_IC(ahB, hb_base, 704)
    LD_IC(ahC, hb_base, 768)  LD_IC(ahD, hb_base, 832)
    LD_IC(ahE, hb_base, 896)  LD_IC(ahF, hb_base, 960)
    bf16x8 au[4];
#pragma unroll
    for (int i = 0; i < 4; ++i)
      au[i] = cvt8s(&Ut[(size_t)arow * UD + i * 32 + klane], dtv);

    asm volatile("s_waitcnt vmcnt(0)" ::: "memory");
    __builtin_amdgcn_sched_barrier(0);

    f32x4 acc[4] = {};
    bf16x8 ah[16] = {ah0, ah1, ah2, ah3, ah4, ah5, ah6, ah7,
                     ah8, ah9, ahA, ahB, ahC, ahD, ahE, ahF};
#pragma unroll
    for (int i = 0; i < 4; ++i) {
#pragma unroll
      for (int g = 0; g < 4; ++g) {
        bf16x8 b = *reinterpret_cast<const bf16x8*>(&W0L[(g * 16 + rm) * KP0 + i * 32 + klane]);
        acc[g] = mfma16(au[i], b, acc[g]);
      }
    }
#pragma unroll
    for (int i = 0; i < 16; ++i) {
#pragma unroll
      for (int g = 0; g < 4; ++g) {
        bf16x8 b = *reinterpret_cast<const bf16x8*>(&W0L[(g * 16 + rm) * KP0 + UD + i * 32 + klane]);
        acc[g] = mfma16(ah[i], b, acc[g]);
      }
    }
#pragma unroll
    for (int q = 0; q < 4; ++q) {
      float gi = acc[0][q] + preR[0][q];
      float gf = acc[1][q] + preR[1][q];
      float gg = acc[2][q] + preR[2][q];
      float go = acc[3][q] + preR[3][q];
      float cn = sigm(gf) * c1v[q] + sigm(gi) * tanhfast(gg);
      c1v[q] = cn;
      float hn = sigm(go) * tanhfast(cn);
      st_ic(&h1buf[(size_t)(rbase + q) * DD + dcol], hn);
    }
    rg_barrier(myflag, flags, r, 2 * t + 1, budget);

    // ---- layer 1: gates = h1 @ (Wih1+Whh1)^T + b1sum ----
    bf16x8 b0, b1, b2, b3, b4, b5, b6, b7;
    bf16x8 b8, b9, bA, bBv, bCv, bDv, bEv, bFv;
    LD_IC(b0, h1_base, 0)    LD_IC(b1, h1_base, 64)
    LD_IC(b2, h1_base, 128)  LD_IC(b3, h1_base, 192)
    LD_IC(b4, h1_base, 256)  LD_IC(b5, h1_base, 320)
    LD_IC(b6, h1_base, 384)  LD_IC(b7, h1_base, 448)
    LD_IC(b8, h1_base, 512)  LD_IC(b9, h1_base, 576)
    LD_IC(bA, h1_base, 640)  LD_IC(bBv, h1_base, 704)
    LD_IC(bCv, h1_base, 768) LD_IC(bDv, h1_base, 832)
    LD_IC(bEv, h1_base, 896) LD_IC(bFv, h1_base, 960)

    asm volatile("s_waitcnt vmcnt(0)" ::: "memory");
    __builtin_amdgcn_sched_barrier(0);

    f32x4 acc2[4] = {};
    bf16x8 a1[16] = {b0, b1, b2, b3, b4, b5, b6, b7,
                     b8, b9, bA, bBv, bCv, bDv, bEv, bFv};
#pragma unroll
    for (int i = 0; i < 16; ++i) {
#pragma unroll
      for (int g = 0; g < 4; ++g) {
        bf16x8 b = *reinterpret_cast<const bf16x8*>(&W1L[(g * 16 + rm) * KP1 + i * 32 + klane]);
        acc2[g] = mfma16(a1[i], b, acc2[g]);
      }
    }
    float* Zt = Z + (size_t)t * BB * DD;
#pragma unroll
    for (int q = 0; q < 4; ++q) {
      float gi = acc2[0][q] + b1R[0];
      float gf = acc2[1][q] + b1R[1];
      float gg = acc2[2][q] + b1R[2];
      float go = acc2[3][q] + b1R[3];
      float cn = sigm(gf) * c2v[q] + sigm(gi) * tanhfast(gg);
      c2v[q] = cn;
      float hn = sigm(go) * tanhfast(cn);
      st_ic(&hbuf[(size_t)(rbase + q) * DD + dcol], hn);
      Zt[(size_t)(rbase + q) * DD + dcol] = hn;   // ordinary store (read next kernel)
    }
    rg_barrier(myflag, flags, r, 2 * t + 2, budget);
  }
}

// ---------------- batched output head: Y = [Z | dt*U] @ CD^T ----------------
__global__ __launch_bounds__(256) void y_kernel(
    const float* __restrict__ Z, const float* __restrict__ U,
    const float* __restrict__ dtp, const __bf16* __restrict__ CD,
    float* __restrict__ Y)
{
  int lane = threadIdx.x & 63, w = threadIdx.x >> 6;
  int rm = lane & 15;
  int rowbase = blockIdx.x * 128 + w * 32;
  int klane = (lane >> 4) * 8;
  float dtv = dtp[0];
  f32x4 acc[2][3] = {};
#pragma unroll
  for (int k0 = 0; k0 < KY; k0 += 32) {
    int k = k0 + klane;
    bf16x8 a[2];
#pragma unroll
    for (int rb = 0; rb < 2; ++rb) {
      int rr = rowbase + rb * 16 + rm;
      if (k0 < DD) a[rb] = cvt8(&Z[(size_t)rr * DD + k]);
      else         a[rb] = cvt8s(&U[(size_t)rr * UD + (k - DD)], dtv);
    }
#pragma unroll
    for (int cf = 0; cf < 3; ++cf) {
      bf16x8 b = *reinterpret_cast<const bf16x8*>(&CD[(size_t)(cf * 16 + rm) * KY + k]);
#pragma unroll
      for (int rb = 0; rb < 2; ++rb) acc[rb][cf] = mfma16(a[rb], b, acc[rb][cf]);
    }
  }
#pragma unroll
  for (int rb = 0; rb < 2; ++rb)
#pragma unroll
    for (int cf = 0; cf < 3; ++cf) {
      int n = cf * 16 + rm;
      if (n < NO)
#pragma unroll
        for (int q = 0; q < 4; ++q) {
          int rr = rowbase + rb * 16 + (lane >> 4) * 4 + q;
          Y[(size_t)rr * NO + n] = acc[rb][cf][q];
        }
    }
}

extern "C" void kernel_launch(void* const* d_in, const int* in_sizes, int n_in,
                              void* d_out, int out_size, void* d_ws, size_t ws_size,
                              hipStream_t stream) {
  const float* z_dyn    = (const float*)d_in[0];
  const float* z_static = (const float*)d_in[1];
  const float* dt       = (const float*)d_in[2];
  const float* U        = (const float*)d_in[3];
  const float* Wih0     = (const float*)d_in[4];
  const float* Whh0     = (const float*)d_in[5];
  const float* bih0     = (const float*)d_in[6];
  const float* bhh0     = (const float*)d_in[7];
  const float* Wih1     = (const float*)d_in[8];
  const float* Whh1     = (const float*)d_in[9];
  const float* bih1     = (const float*)d_in[10];
  const float* bhh1     = (const float*)d_in[11];
  const float* Cw       = (const float*)d_in[12];
  const float* Dw       = (const float*)d_in[13];

  float* out = (float*)d_out;
  float* Z = out;                                       // [TT, BB, DD]
  float* Y = out + (size_t)TT * BB * DD;                // [TT, BB, NO]

  char* p = (char*)d_ws;
  auto carve = [&](size_t bytes) {
    void* r = (void*)p;
    p += (bytes + 255) & ~(size_t)255;
    return r;
  };
  float*  b1sum  = (float*)carve((size_t)G4 * 4);
  __bf16* CD     = (__bf16*)carve((size_t)NY * KY * 2);
  float*  pre0   = (float*)carve((size_t)BB * G4 * 4);
  __bf16* hbuf   = (__bf16*)carve((size_t)BB * DD * 2);
  __bf16* h1buf  = (__bf16*)carve((size_t)BB * DD * 2);
  int*    flags  = (int*)carve((size_t)NRG * NCS * 16 * 4);

  prep_kernel<<<1024, 256, 0, stream>>>(z_dyn, bih1, bhh1, Cw, Dw,
                                        b1sum, CD, hbuf, flags);
  pre0_kernel<<<dim3(8, 32), 256, 0, stream>>>(z_static, Wih0, bih0, bhh0, pre0);

  persist_kernel<<<256, 256, LDSB, stream>>>(
      U, dt, Wih0, Whh0, Wih1, Whh1, pre0, b1sum, hbuf, h1buf, flags, Z);

  y_kernel<<<512, 256, 0, stream>>>(Z, U, dt, CD, Y);
}